// Round 6
// baseline (279.669 us; speedup 1.0000x reference)
//
#include <hip/hip_runtime.h>
#include <hip/hip_bf16.h>
#include <cstdint>
#include <cstddef>

#define N_NODES 50000
#define DEG     24
#define NEDGE   (N_NODES*DEG)
#define RSZ     500
#define NDIM    64
#define FEATD   192

// LDS row stride (shorts) for the 16x200 per-wave transpose buffer in k_gate.
#define LSTR    200

// k_layer: 64 nodes/block, gather window rows [B0+1, B0+224] staged in LDS.
#define WNODES  64
#define WROWS   225
#define WSTR    72          // floats; 288B rows: 16B-aligned, banks spread
#define LGRID   784         // 8 XCD chunks x 98
#define LCHUNK  98

typedef short bf16x8 __attribute__((ext_vector_type(8)));
typedef float f32x4  __attribute__((ext_vector_type(4)));

__device__ __forceinline__ unsigned short f2bf(float f) {
    unsigned u = __builtin_bit_cast(unsigned, f);
    unsigned r = (u + 0x7fffu + ((u >> 16) & 1u)) >> 16;   // RNE
    return (unsigned short)r;
}
__device__ __forceinline__ float bf2f(unsigned short s) {
    unsigned u = ((unsigned)s) << 16;
    return __builtin_bit_cast(float, u);
}
__device__ __forceinline__ float fast_tanh(float x) {
    float e = __expf(2.f * x);
    return 1.f - 2.f / (e + 1.f);
}

// ---- PREP (fused): tanh(features)->fin0 | l2norm(rel)+exp(attdot) |
//      1/||proxy_n|| | pack B1/B2/B3 | pack edges.
// Block ranges: [0,3125) tanh, [3125,3250) rel, [3250,3266) pninv,
//               [3266,3506) packB, [3506,4678) packE.
__global__ __launch_bounds__(256) void k_prep(const float* __restrict__ features,
                                              const float* __restrict__ rel_emb,
                                              const float* __restrict__ attn_k,
                                              const float* __restrict__ proxy,
                                              const float* __restrict__ gate_w,
                                              const int* __restrict__ src,
                                              const int* __restrict__ rel,
                                              float* __restrict__ fin0,
                                              float* __restrict__ reln,
                                              float* __restrict__ expdot,
                                              float* __restrict__ pninv,
                                              unsigned short* __restrict__ B1,
                                              unsigned short* __restrict__ B2,
                                              unsigned short* __restrict__ B3,
                                              unsigned int* __restrict__ pedge) {
    int b = blockIdx.x;
    if (b < 3125) {
        int t = b * 256 + threadIdx.x;             // 800000 threads, 4 elems each
        int idx4 = t * 4;
        float4 f = *reinterpret_cast<const float4*>(features + idx4);
        float4 o;
        o.x = fast_tanh(f.x); o.y = fast_tanh(f.y);
        o.z = fast_tanh(f.z); o.w = fast_tanh(f.w);
        *reinterpret_cast<float4*>(fin0 + idx4) = o;
    } else if (b < 3250) {
        int lane = threadIdx.x & 63;
        int row = (b - 3125) * 4 + (threadIdx.x >> 6);   // 500 rows
        float v = rel_emb[row * 64 + lane];
        float ss = v * v;
        for (int m = 1; m < 64; m <<= 1) ss += __shfl_xor(ss, m);
        float inv = 1.f / fmaxf(sqrtf(ss), 1e-12f);
        float rn = v * inv;
        reln[row * 64 + lane] = rn;
        float d0 = rn * attn_k[lane];
        float d1 = rn * attn_k[64 + lane];
        for (int m = 1; m < 64; m <<= 1) { d0 += __shfl_xor(d0, m); d1 += __shfl_xor(d1, m); }
        if (lane == 0) { expdot[row] = __expf(d0); expdot[RSZ + row] = __expf(d1); }
    } else if (b < 3266) {
        int lane = threadIdx.x & 63;
        int row = (b - 3250) * 4 + (threadIdx.x >> 6);   // 64 rows
        const float* p = proxy + (size_t)row * FEATD;
        float a = p[lane], bb = p[64 + lane], c = p[128 + lane];
        float ss = a * a + bb * bb + c * c;
        for (int m = 1; m < 64; m <<= 1) ss += __shfl_xor(ss, m);
        if (lane == 0) pninv[row] = 1.f / fmaxf(sqrtf(ss), 1e-12f);
    } else if (b < 3506) {
        // B-frag for 16x16x32: lane holds B[k=(lane>>4)*8+j][n=lane&15], j=0..7
        int idx = (b - 3266) * 256 + threadIdx.x;        // 61440 threads
        int j = idx & 7, lane = (idx >> 3) & 63;
        int t = idx >> 9;
        int lane16 = lane & 15, quad = lane >> 4;
        if (t < 24) {                 // B1: Bmat[k][n] = proxy[n][k] (pninv applied later)
            int kt = t >> 2, nt = t & 3;
            int k = kt * 32 + quad * 8 + j, n = nt * 16 + lane16;
            B1[idx] = f2bf(proxy[(size_t)n * FEATD + k]);
        } else if (t < 48) {          // B2: pa@proxy, Bmat[k][n] = proxy[k][n]
            int tt = t - 24, kt = tt / 12, nt = tt % 12;
            int k = kt * 32 + quad * 8 + j, n = nt * 16 + lane16;
            B2[idx - 12288] = f2bf(proxy[(size_t)k * FEATD + n]);
        } else {                      // B3: pf@gate_w^T, Bmat[k][n] = gate_w[n][k]
            int tt = t - 48, kt = tt / 12, nt = tt % 12;
            int k = kt * 32 + quad * 8 + j, n = nt * 16 + lane16;
            B3[idx - 24576] = f2bf(gate_w[(size_t)n * FEATD + k]);
        }
    } else {
        // pack edges: pe = s | (r<<16)   (s < 65536, r < 512)
        int t = (b - 3506) * 256 + threadIdx.x;          // need 300000
        if (t < NEDGE / 4) {
            int4 s4 = *reinterpret_cast<const int4*>(src + t * 4);
            int4 r4 = *reinterpret_cast<const int4*>(rel + t * 4);
            uint4 o;
            o.x = (unsigned)s4.x | ((unsigned)r4.x << 16);
            o.y = (unsigned)s4.y | ((unsigned)r4.y << 16);
            o.z = (unsigned)s4.z | ((unsigned)r4.z << 16);
            o.w = (unsigned)s4.w | ((unsigned)r4.w << 16);
            *reinterpret_cast<uint4*>(pedge + t * 4) = o;
        }
    }
}

// ---- Layer: LDS-windowed gather ---------------------------------------------
// Graph structure: col = row + 1 + 7k (mod N) -> a 64-node block's entire
// gather set lies in rows [B0+1, B0+224]. Stage that window in LDS once;
// gathers become conflict-free ds_read_b128 (bank = (8*li + 4*lane16)%32:
// each bank gets exactly 8 dwords per access = HW minimum). Guarded global
// fallback if an index ever leaves the window (never taken on this graph).
// 16 lanes/node, 4 nodes/wave, 4 sequential groups -> 64 nodes/block.
__global__ __launch_bounds__(256) void k_layer(const unsigned int* __restrict__ pedge,
                                               const float* __restrict__ reln,
                                               const float* __restrict__ expdot_l,
                                               const float* __restrict__ fin,
                                               float* __restrict__ fout) {
    __shared__ float W[WROWS * WSTR];                    // 64800 B
    int b = blockIdx.x;
    int lb = (b & 7) * LCHUNK + (b >> 3);                // XCD-contiguous ranges
    int B0 = lb * WNODES;
    if (B0 >= N_NODES) return;                           // whole block exits pre-barrier

    // stage window rows (B0+1 .. B0+225) mod N of fin into LDS (contiguous read)
    for (int i = threadIdx.x; i < WROWS * 16; i += 256) {
        int row = i >> 4, c4 = (i & 15) * 4;
        int g = B0 + 1 + row; if (g >= N_NODES) g -= N_NODES;
        float4 v = *reinterpret_cast<const float4*>(fin + (size_t)g * 64 + c4);
        *reinterpret_cast<float4*>(W + row * WSTR + c4) = v;
    }
    __syncthreads();

    int lane16 = threadIdx.x & 15;
    int wv = threadIdx.x >> 6;           // wave 0..3
    int sub = (threadIdx.x >> 4) & 3;    // node-in-wave 0..3 (consecutive nodes)

#pragma unroll
    for (int g = 0; g < 4; g++) {
        int node = B0 + ((g << 2) | wv) * 4 + sub;       // wave holds 4 consecutive
        bool valid = node < N_NODES;
        int ebase = valid ? node * DEG : 0;
        float a0 = 0.f, a1 = 0.f, a2 = 0.f, a3 = 0.f, den = 0.f;
#pragma unroll 8
        for (int k = 0; k < DEG; k++) {
            unsigned pe = pedge[ebase + k];              // node-uniform: HW broadcast
            int s = pe & 0xFFFF, r = pe >> 16;
            float ex = expdot_l[r];
            float4 tv = *reinterpret_cast<const float4*>(reln + (size_t)r * 64 + lane16 * 4);
            int li = s - B0 - 1; if (li < 0) li += N_NODES;
            float4 nv;
            if (li < WROWS) nv = *reinterpret_cast<const float4*>(W + li * WSTR + lane16 * 4);
            else            nv = *reinterpret_cast<const float4*>(fin + (size_t)s * 64 + lane16 * 4);
            float pd = tv.x * nv.x + tv.y * nv.y + tv.z * nv.z + tv.w * nv.w;
            pd += __shfl_xor(pd, 1); pd += __shfl_xor(pd, 2);
            pd += __shfl_xor(pd, 4); pd += __shfl_xor(pd, 8);
            float t1 = -2.f * pd * ex;                   // acc += ex*(nv - 2*dot*tv)
            a0 = fmaf(ex, nv.x, fmaf(t1, tv.x, a0));
            a1 = fmaf(ex, nv.y, fmaf(t1, tv.y, a1));
            a2 = fmaf(ex, nv.z, fmaf(t1, tv.z, a2));
            a3 = fmaf(ex, nv.w, fmaf(t1, tv.w, a3));
            den += ex;
        }
        if (valid) {
            float id = 1.f / den;
            float4 o;
            o.x = fast_tanh(a0 * id); o.y = fast_tanh(a1 * id);
            o.z = fast_tanh(a2 * id); o.w = fast_tanh(a3 * id);
            *reinterpret_cast<float4*>(fout + (size_t)node * 64 + lane16 * 4) = o;
        }
    }
}

// ---- GATE (fused G1+G2+G3) — R4-proven version ------------------------------
__global__ __launch_bounds__(256) void k_gate(const float* __restrict__ fin0,
                                              const float* __restrict__ fin1,
                                              const float* __restrict__ fin2,
                                              const unsigned short* __restrict__ B1,
                                              const unsigned short* __restrict__ B2,
                                              const unsigned short* __restrict__ B3,
                                              const float* __restrict__ pninv,
                                              const float* __restrict__ gate_b,
                                              float* __restrict__ dout) {
    __shared__ unsigned short lds[4][16 * LSTR];
    int wv = threadIdx.x >> 6, lane = threadIdx.x & 63;
    int tile = blockIdx.x * 4 + wv;
    if (tile > N_NODES / 16 - 1) tile = N_NODES / 16 - 1;  // dup work, identical writes
    int row0 = tile * 16, lane16 = lane & 15, quad = lane >> 4;
    unsigned short* L = lds[wv];
    const float* fsel[3] = {fin0, fin1, fin2};

    float oreg[12][4];
#pragma unroll
    for (int nt = 0; nt < 12; nt++) {
        const float* f = fsel[nt >> 2];
#pragma unroll
        for (int r = 0; r < 4; r++)
            oreg[nt][r] = f[(size_t)(row0 + quad * 4 + r) * 64 + (nt & 3) * 16 + lane16];
    }

    bf16x8 af[6];
    float ss = 0.f;
#pragma unroll
    for (int kt = 0; kt < 6; kt++) {
        const float* f = fsel[kt >> 1];
        const float* arow = f + (size_t)(row0 + lane16) * 64 + (kt & 1) * 32 + quad * 8;
        float4 p0 = *reinterpret_cast<const float4*>(arow);
        float4 p1 = *reinterpret_cast<const float4*>(arow + 4);
        ss += p0.x * p0.x + p0.y * p0.y + p0.z * p0.z + p0.w * p0.w;
        ss += p1.x * p1.x + p1.y * p1.y + p1.z * p1.z + p1.w * p1.w;
        bf16x8 a;
        a[0] = (short)f2bf(p0.x); a[1] = (short)f2bf(p0.y);
        a[2] = (short)f2bf(p0.z); a[3] = (short)f2bf(p0.w);
        a[4] = (short)f2bf(p1.x); a[5] = (short)f2bf(p1.y);
        a[6] = (short)f2bf(p1.z); a[7] = (short)f2bf(p1.w);
        af[kt] = a;
    }
    ss += __shfl_xor(ss, 16); ss += __shfl_xor(ss, 32);
    float inv = 1.f / fmaxf(sqrtf(ss), 1e-12f);
    float pni[4];
#pragma unroll
    for (int nt = 0; nt < 4; nt++) pni[nt] = pninv[nt * 16 + lane16];
    f32x4 acc4[4];
#pragma unroll
    for (int nt = 0; nt < 4; nt++) acc4[nt] = (f32x4){0.f, 0.f, 0.f, 0.f};
#pragma unroll
    for (int kt = 0; kt < 6; kt++) {
#pragma unroll
        for (int nt = 0; nt < 4; nt++) {
            bf16x8 bfr = *reinterpret_cast<const bf16x8*>(B1 + ((size_t)(kt * 4 + nt) * 64 + lane) * 8);
            acc4[nt] = __builtin_amdgcn_mfma_f32_16x16x32_bf16(af[kt], bfr, acc4[nt], 0, 0, 0);
        }
    }
    // softmax without max-sub: logits are cosine sims in [-1,1]
#pragma unroll
    for (int r = 0; r < 4; r++) {
        int rowloc = quad * 4 + r;
        float invr = __shfl(inv, rowloc);
        float e0 = __expf(acc4[0][r] * invr * pni[0]);
        float e1 = __expf(acc4[1][r] * invr * pni[1]);
        float e2 = __expf(acc4[2][r] * invr * pni[2]);
        float e3 = __expf(acc4[3][r] * invr * pni[3]);
        float s = e0 + e1 + e2 + e3;
        s += __shfl_xor(s, 1); s += __shfl_xor(s, 2);
        s += __shfl_xor(s, 4); s += __shfl_xor(s, 8);
        float rs = 1.f / s;
        L[rowloc * LSTR + lane16]      = f2bf(e0 * rs);
        L[rowloc * LSTR + 16 + lane16] = f2bf(e1 * rs);
        L[rowloc * LSTR + 32 + lane16] = f2bf(e2 * rs);
        L[rowloc * LSTR + 48 + lane16] = f2bf(e3 * rs);
    }
    __threadfence_block();

    f32x4 acc[12];
#pragma unroll
    for (int nt = 0; nt < 12; nt++) acc[nt] = (f32x4){0.f, 0.f, 0.f, 0.f};
#pragma unroll
    for (int kt = 0; kt < 2; kt++) {
        bf16x8 a = *reinterpret_cast<const bf16x8*>(L + lane16 * LSTR + kt * 32 + quad * 8);
#pragma unroll
        for (int nt = 0; nt < 12; nt++) {
            bf16x8 bfr = *reinterpret_cast<const bf16x8*>(B2 + ((size_t)(kt * 12 + nt) * 64 + lane) * 8);
            acc[nt] = __builtin_amdgcn_mfma_f32_16x16x32_bf16(a, bfr, acc[nt], 0, 0, 0);
        }
    }
    __threadfence_block();
#pragma unroll
    for (int nt = 0; nt < 12; nt++) {
#pragma unroll
        for (int r = 0; r < 4; r++) {
            int rowloc = quad * 4 + r;
            L[rowloc * LSTR + nt * 16 + lane16] = f2bf(oreg[nt][r] - acc[nt][r]);
        }
    }
    __threadfence_block();

#pragma unroll
    for (int nt = 0; nt < 12; nt++) acc[nt] = (f32x4){0.f, 0.f, 0.f, 0.f};
#pragma unroll
    for (int kt = 0; kt < 6; kt++) {
        bf16x8 a = *reinterpret_cast<const bf16x8*>(L + lane16 * LSTR + kt * 32 + quad * 8);
#pragma unroll
        for (int nt = 0; nt < 12; nt++) {
            bf16x8 bfr = *reinterpret_cast<const bf16x8*>(B3 + ((size_t)(kt * 12 + nt) * 64 + lane) * 8);
            acc[nt] = __builtin_amdgcn_mfma_f32_16x16x32_bf16(a, bfr, acc[nt], 0, 0, 0);
        }
    }

#pragma unroll
    for (int nt = 0; nt < 12; nt++) {
        float bias = gate_b[nt * 16 + lane16];
#pragma unroll
        for (int r = 0; r < 4; r++) {
            int rowloc = quad * 4 + r;
            size_t idx = (size_t)(row0 + rowloc) * FEATD + nt * 16 + lane16;
            float z = acc[nt][r] + bias;
            float g = 1.f / (1.f + __expf(-z));
            float pf = bf2f(L[rowloc * LSTR + nt * 16 + lane16]);
            dout[idx] = pf + g * (oreg[nt][r] - pf);
        }
    }
}

extern "C" void kernel_launch(void* const* d_in, const int* in_sizes, int n_in,
                              void* d_out, int out_size, void* d_ws, size_t ws_size,
                              hipStream_t stream) {
    (void)in_sizes; (void)n_in; (void)out_size; (void)ws_size;
    const float* features = (const float*)d_in[0];
    const float* rel_emb  = (const float*)d_in[1];
    const float* proxy    = (const float*)d_in[2];
    const float* gate_w   = (const float*)d_in[3];
    const float* gate_b   = (const float*)d_in[4];
    const float* attn_k   = (const float*)d_in[5];
    const int*   adj      = (const int*)d_in[6];
    const int*   r_index  = (const int*)d_in[7];
    // d_in[8] (r_val) unused: positive scale cancels under l2norm; r_index[0]==arange(E).

    float* fin0    = (float*)d_ws;                          // N*64 fp32
    float* fin1    = fin0 + (size_t)N_NODES * 64;           // N*64 fp32
    float* fin2    = fin1 + (size_t)N_NODES * 64;           // N*64 fp32
    float* reln    = fin2 + (size_t)N_NODES * 64;           // 500*64
    float* expdot  = reln + RSZ * 64;                       // 2*500
    float* pninv   = expdot + 2 * RSZ;                      // 64
    unsigned short* B1 = (unsigned short*)(pninv + 64);     // 12288
    unsigned short* B2 = B1 + 12288;                        // 12288
    unsigned short* B3 = B2 + 12288;                        // 36864
    unsigned int* pedge = (unsigned int*)(B3 + 36864);      // NEDGE u32

    const int* src = adj + NEDGE;       // adj[1]
    const int* rel = r_index + NEDGE;   // r_index[1]

    k_prep  <<<dim3(4678), dim3(256), 0, stream>>>(features, rel_emb, attn_k, proxy, gate_w,
                                                   src, rel, fin0, reln, expdot,
                                                   pninv, B1, B2, B3, pedge);
    k_layer <<<dim3(LGRID), dim3(256), 0, stream>>>(pedge, reln, expdot,       fin0, fin1);
    k_layer <<<dim3(LGRID), dim3(256), 0, stream>>>(pedge, reln, expdot + RSZ, fin1, fin2);
    k_gate  <<<dim3(782),  dim3(256), 0, stream>>>(fin0, fin1, fin2, B1, B2, B3, pninv,
                                                   gate_b, (float*)d_out);
}

// Round 7
// 185.550 us; speedup vs baseline: 1.5072x; 1.5072x over previous
//
#include <hip/hip_runtime.h>
#include <hip/hip_bf16.h>
#include <cstdint>
#include <cstddef>

#define N_NODES 50000
#define DEG     24
#define NEDGE   (N_NODES*DEG)
#define RSZ     500
#define NDIM    64
#define FEATD   192

// LDS row stride (shorts) for the 16x200 per-wave transpose buffer in k_gate.
#define LSTR    200

// k_layer grid: 32 nodes/block (8 lanes x 8 dims per node), 1563 logical blocks,
// padded to 1568 = 8*196 for the XCD swizzle.
#define LGRID   1568
#define LCHUNK  196

typedef short bf16x8 __attribute__((ext_vector_type(8)));
typedef float f32x4  __attribute__((ext_vector_type(4)));

__device__ __forceinline__ unsigned short f2bf(float f) {
    unsigned u = __builtin_bit_cast(unsigned, f);
    unsigned r = (u + 0x7fffu + ((u >> 16) & 1u)) >> 16;   // RNE
    return (unsigned short)r;
}
__device__ __forceinline__ float bf2f(unsigned short s) {
    unsigned u = ((unsigned)s) << 16;
    return __builtin_bit_cast(float, u);
}
__device__ __forceinline__ float lo16(unsigned u) {       // low bf16 of a dword
    return __builtin_bit_cast(float, u << 16);
}
__device__ __forceinline__ float hi16(unsigned u) {       // high bf16 of a dword
    return __builtin_bit_cast(float, u & 0xFFFF0000u);
}
__device__ __forceinline__ float fast_tanh(float x) {
    float e = __expf(2.f * x);
    return 1.f - 2.f / (e + 1.f);
}

// ---- PREP (fused): tanh(features)->fin0 (bf16) | l2norm(rel)+exp(attdot) |
//      1/||proxy_n|| | pack B1/B2/B3 | pack edges.
// Block ranges: [0,3125) tanh, [3125,3250) rel, [3250,3266) pninv,
//               [3266,3506) packB, [3506,4678) packE.
__global__ __launch_bounds__(256) void k_prep(const float* __restrict__ features,
                                              const float* __restrict__ rel_emb,
                                              const float* __restrict__ attn_k,
                                              const float* __restrict__ proxy,
                                              const float* __restrict__ gate_w,
                                              const int* __restrict__ src,
                                              const int* __restrict__ rel,
                                              unsigned short* __restrict__ fin0,
                                              float* __restrict__ reln,
                                              float* __restrict__ expdot,
                                              float* __restrict__ pninv,
                                              unsigned short* __restrict__ B1,
                                              unsigned short* __restrict__ B2,
                                              unsigned short* __restrict__ B3,
                                              unsigned int* __restrict__ pedge) {
    int b = blockIdx.x;
    if (b < 3125) {
        int t = b * 256 + threadIdx.x;             // 800000 threads, 4 elems each
        int idx4 = t * 4;
        float4 f = *reinterpret_cast<const float4*>(features + idx4);
        uint2 w;
        w.x = (unsigned)f2bf(fast_tanh(f.x)) | ((unsigned)f2bf(fast_tanh(f.y)) << 16);
        w.y = (unsigned)f2bf(fast_tanh(f.z)) | ((unsigned)f2bf(fast_tanh(f.w)) << 16);
        *reinterpret_cast<uint2*>(fin0 + idx4) = w;
    } else if (b < 3250) {
        int lane = threadIdx.x & 63;
        int row = (b - 3125) * 4 + (threadIdx.x >> 6);   // 500 rows
        float v = rel_emb[row * 64 + lane];
        float ss = v * v;
        for (int m = 1; m < 64; m <<= 1) ss += __shfl_xor(ss, m);
        float inv = 1.f / fmaxf(sqrtf(ss), 1e-12f);
        float rn = v * inv;
        reln[row * 64 + lane] = rn;
        float d0 = rn * attn_k[lane];
        float d1 = rn * attn_k[64 + lane];
        for (int m = 1; m < 64; m <<= 1) { d0 += __shfl_xor(d0, m); d1 += __shfl_xor(d1, m); }
        if (lane == 0) { expdot[row] = __expf(d0); expdot[RSZ + row] = __expf(d1); }
    } else if (b < 3266) {
        int lane = threadIdx.x & 63;
        int row = (b - 3250) * 4 + (threadIdx.x >> 6);   // 64 rows
        const float* p = proxy + (size_t)row * FEATD;
        float a = p[lane], bb = p[64 + lane], c = p[128 + lane];
        float ss = a * a + bb * bb + c * c;
        for (int m = 1; m < 64; m <<= 1) ss += __shfl_xor(ss, m);
        if (lane == 0) pninv[row] = 1.f / fmaxf(sqrtf(ss), 1e-12f);
    } else if (b < 3506) {
        // B-frag for 16x16x32: lane holds B[k=(lane>>4)*8+j][n=lane&15], j=0..7
        int idx = (b - 3266) * 256 + threadIdx.x;        // 61440 threads
        int j = idx & 7, lane = (idx >> 3) & 63;
        int t = idx >> 9;
        int lane16 = lane & 15, quad = lane >> 4;
        if (t < 24) {                 // B1: Bmat[k][n] = proxy[n][k] (pninv applied later)
            int kt = t >> 2, nt = t & 3;
            int k = kt * 32 + quad * 8 + j, n = nt * 16 + lane16;
            B1[idx] = f2bf(proxy[(size_t)n * FEATD + k]);
        } else if (t < 48) {          // B2: pa@proxy, Bmat[k][n] = proxy[k][n]
            int tt = t - 24, kt = tt / 12, nt = tt % 12;
            int k = kt * 32 + quad * 8 + j, n = nt * 16 + lane16;
            B2[idx - 12288] = f2bf(proxy[(size_t)k * FEATD + n]);
        } else {                      // B3: pf@gate_w^T, Bmat[k][n] = gate_w[n][k]
            int tt = t - 48, kt = tt / 12, nt = tt % 12;
            int k = kt * 32 + quad * 8 + j, n = nt * 16 + lane16;
            B3[idx - 24576] = f2bf(gate_w[(size_t)n * FEATD + k]);
        }
    } else {
        // pack edges: pe = s | (r<<16)   (s < 65536, r < 512)
        int t = (b - 3506) * 256 + threadIdx.x;          // need 300000
        if (t < NEDGE / 4) {
            int4 s4 = *reinterpret_cast<const int4*>(src + t * 4);
            int4 r4 = *reinterpret_cast<const int4*>(rel + t * 4);
            uint4 o;
            o.x = (unsigned)s4.x | ((unsigned)r4.x << 16);
            o.y = (unsigned)s4.y | ((unsigned)r4.y << 16);
            o.z = (unsigned)s4.z | ((unsigned)r4.z << 16);
            o.w = (unsigned)s4.w | ((unsigned)r4.w << 16);
            *reinterpret_cast<uint4*>(pedge + t * 4) = o;
        }
    }
}

// ---- Layer: per-node attention aggregation (R4-proven shape, bf16 feats) ----
// 8 lanes per node, 8 dims per lane. bf16 fin[N][64] -> bf16 fout[N][64]:
// gather = ONE dwordx4 (16B) per lane. reln stays fp32 (reflection accuracy).
// XCD swizzle: each XCD gets a contiguous node range (gather window in its L2).
__global__ __launch_bounds__(256) void k_layer(const unsigned int* __restrict__ pedge,
                                               const float* __restrict__ reln,
                                               const float* __restrict__ expdot_l,
                                               const unsigned short* __restrict__ fin,
                                               unsigned short* __restrict__ fout) {
    int b = blockIdx.x;
    int lb = (b & 7) * LCHUNK + (b >> 3);
    int lane8 = threadIdx.x & 7;
    int node = lb * 32 + (threadIdx.x >> 3);
    if (node >= N_NODES) return;
    int ebase = node * DEG;
    // Preload all packed edge indices: no idx-load -> gather dependence.
    unsigned pk[DEG];
#pragma unroll
    for (int k = 0; k < DEG; k++) pk[k] = pedge[ebase + k];
    float a0 = 0.f, a1 = 0.f, a2 = 0.f, a3 = 0.f;
    float a4 = 0.f, a5 = 0.f, a6 = 0.f, a7 = 0.f, den = 0.f;
#pragma unroll 4
    for (int k = 0; k < DEG; k++) {
        unsigned p = pk[k];
        int s = p & 0xFFFF;
        int r = p >> 16;
        float ex = expdot_l[r];
        const float* tp = reln + (size_t)r * 64 + lane8 * 8;
        float4 t0 = *reinterpret_cast<const float4*>(tp);
        float4 t1v = *reinterpret_cast<const float4*>(tp + 4);
        uint4 u = *reinterpret_cast<const uint4*>(fin + (size_t)s * 64 + lane8 * 8);
        float n0 = lo16(u.x), n1 = hi16(u.x), n2 = lo16(u.y), n3 = hi16(u.y);
        float n4 = lo16(u.z), n5 = hi16(u.z), n6 = lo16(u.w), n7 = hi16(u.w);
        float pd = t0.x * n0 + t0.y * n1 + t0.z * n2 + t0.w * n3
                 + t1v.x * n4 + t1v.y * n5 + t1v.z * n6 + t1v.w * n7;
        pd += __shfl_xor(pd, 1); pd += __shfl_xor(pd, 2); pd += __shfl_xor(pd, 4);
        float t1 = -2.f * pd * ex;          // acc += ex*(nv - 2*dot*tv)
        a0 = fmaf(ex, n0, fmaf(t1, t0.x, a0));
        a1 = fmaf(ex, n1, fmaf(t1, t0.y, a1));
        a2 = fmaf(ex, n2, fmaf(t1, t0.z, a2));
        a3 = fmaf(ex, n3, fmaf(t1, t0.w, a3));
        a4 = fmaf(ex, n4, fmaf(t1, t1v.x, a4));
        a5 = fmaf(ex, n5, fmaf(t1, t1v.y, a5));
        a6 = fmaf(ex, n6, fmaf(t1, t1v.z, a6));
        a7 = fmaf(ex, n7, fmaf(t1, t1v.w, a7));
        den += ex;
    }
    float id = 1.f / den;
    uint4 w;
    w.x = (unsigned)f2bf(fast_tanh(a0 * id)) | ((unsigned)f2bf(fast_tanh(a1 * id)) << 16);
    w.y = (unsigned)f2bf(fast_tanh(a2 * id)) | ((unsigned)f2bf(fast_tanh(a3 * id)) << 16);
    w.z = (unsigned)f2bf(fast_tanh(a4 * id)) | ((unsigned)f2bf(fast_tanh(a5 * id)) << 16);
    w.w = (unsigned)f2bf(fast_tanh(a6 * id)) | ((unsigned)f2bf(fast_tanh(a7 * id)) << 16);
    *reinterpret_cast<uint4*>(fout + (size_t)node * 64 + lane8 * 8) = w;
}

// ---- GATE (fused G1+G2+G3) — R4-proven structure, bf16 feat inputs ----------
// A-fragments now load DIRECTLY from bf16 rows (no f2bf chain). Wave-private
// LDS transpose buffer; no s_barrier.
__global__ __launch_bounds__(256) void k_gate(const unsigned short* __restrict__ fin0,
                                              const unsigned short* __restrict__ fin1,
                                              const unsigned short* __restrict__ fin2,
                                              const unsigned short* __restrict__ B1,
                                              const unsigned short* __restrict__ B2,
                                              const unsigned short* __restrict__ B3,
                                              const float* __restrict__ pninv,
                                              const float* __restrict__ gate_b,
                                              float* __restrict__ dout) {
    __shared__ unsigned short lds[4][16 * LSTR];
    int wv = threadIdx.x >> 6, lane = threadIdx.x & 63;
    int tile = blockIdx.x * 4 + wv;
    if (tile > N_NODES / 16 - 1) tile = N_NODES / 16 - 1;  // dup work, identical writes
    int row0 = tile * 16, lane16 = lane & 15, quad = lane >> 4;
    unsigned short* L = lds[wv];
    const unsigned short* fsel[3] = {fin0, fin1, fin2};

    // o in C-layout (rows quad*4+r, col nt*16+lane16) — independent, issue early
    float oreg[12][4];
#pragma unroll
    for (int nt = 0; nt < 12; nt++) {
        const unsigned short* f = fsel[nt >> 2];
#pragma unroll
        for (int r = 0; r < 4; r++)
            oreg[nt][r] = bf2f(f[(size_t)(row0 + quad * 4 + r) * 64 + (nt & 3) * 16 + lane16]);
    }

    // af: direct 16B bf16 A-fragment loads; sumsq via cvt
    bf16x8 af[6];
    float ss = 0.f;
#pragma unroll
    for (int kt = 0; kt < 6; kt++) {
        const unsigned short* f = fsel[kt >> 1];
        bf16x8 a = *reinterpret_cast<const bf16x8*>(f + (size_t)(row0 + lane16) * 64 + (kt & 1) * 32 + quad * 8);
        af[kt] = a;
#pragma unroll
        for (int i = 0; i < 8; i++) {
            float v = bf2f((unsigned short)a[i]);
            ss = fmaf(v, v, ss);
        }
    }
    ss += __shfl_xor(ss, 16); ss += __shfl_xor(ss, 32);   // full row sumsq at lane&15
    float inv = 1.f / fmaxf(sqrtf(ss), 1e-12f);
    float pni[4];
#pragma unroll
    for (int nt = 0; nt < 4; nt++) pni[nt] = pninv[nt * 16 + lane16];
    f32x4 acc4[4];
#pragma unroll
    for (int nt = 0; nt < 4; nt++) acc4[nt] = (f32x4){0.f, 0.f, 0.f, 0.f};
#pragma unroll
    for (int kt = 0; kt < 6; kt++) {
#pragma unroll
        for (int nt = 0; nt < 4; nt++) {
            bf16x8 bfr = *reinterpret_cast<const bf16x8*>(B1 + ((size_t)(kt * 4 + nt) * 64 + lane) * 8);
            acc4[nt] = __builtin_amdgcn_mfma_f32_16x16x32_bf16(af[kt], bfr, acc4[nt], 0, 0, 0);
        }
    }
    // softmax without max-sub: logits are cosine sims in [-1,1]
#pragma unroll
    for (int r = 0; r < 4; r++) {
        int rowloc = quad * 4 + r;
        float invr = __shfl(inv, rowloc);
        float e0 = __expf(acc4[0][r] * invr * pni[0]);
        float e1 = __expf(acc4[1][r] * invr * pni[1]);
        float e2 = __expf(acc4[2][r] * invr * pni[2]);
        float e3 = __expf(acc4[3][r] * invr * pni[3]);
        float s = e0 + e1 + e2 + e3;
        s += __shfl_xor(s, 1); s += __shfl_xor(s, 2);
        s += __shfl_xor(s, 4); s += __shfl_xor(s, 8);
        float rs = 1.f / s;
        L[rowloc * LSTR + lane16]      = f2bf(e0 * rs);
        L[rowloc * LSTR + 16 + lane16] = f2bf(e1 * rs);
        L[rowloc * LSTR + 32 + lane16] = f2bf(e2 * rs);
        L[rowloc * LSTR + 48 + lane16] = f2bf(e3 * rs);
    }
    __threadfence_block();   // drain pa writes (wave-private LDS; no s_barrier)

    f32x4 acc[12];
#pragma unroll
    for (int nt = 0; nt < 12; nt++) acc[nt] = (f32x4){0.f, 0.f, 0.f, 0.f};
#pragma unroll
    for (int kt = 0; kt < 2; kt++) {
        bf16x8 a = *reinterpret_cast<const bf16x8*>(L + lane16 * LSTR + kt * 32 + quad * 8);
#pragma unroll
        for (int nt = 0; nt < 12; nt++) {
            bf16x8 bfr = *reinterpret_cast<const bf16x8*>(B2 + ((size_t)(kt * 12 + nt) * 64 + lane) * 8);
            acc[nt] = __builtin_amdgcn_mfma_f32_16x16x32_bf16(a, bfr, acc[nt], 0, 0, 0);
        }
    }
    __threadfence_block();   // pa reads complete before pf overwrites rows
#pragma unroll
    for (int nt = 0; nt < 12; nt++) {
#pragma unroll
        for (int r = 0; r < 4; r++) {
            int rowloc = quad * 4 + r;
            L[rowloc * LSTR + nt * 16 + lane16] = f2bf(oreg[nt][r] - acc[nt][r]);
        }
    }
    __threadfence_block();   // drain pf writes

#pragma unroll
    for (int nt = 0; nt < 12; nt++) acc[nt] = (f32x4){0.f, 0.f, 0.f, 0.f};
#pragma unroll
    for (int kt = 0; kt < 6; kt++) {
        bf16x8 a = *reinterpret_cast<const bf16x8*>(L + lane16 * LSTR + kt * 32 + quad * 8);
#pragma unroll
        for (int nt = 0; nt < 12; nt++) {
            bf16x8 bfr = *reinterpret_cast<const bf16x8*>(B3 + ((size_t)(kt * 12 + nt) * 64 + lane) * 8);
            acc[nt] = __builtin_amdgcn_mfma_f32_16x16x32_bf16(a, bfr, acc[nt], 0, 0, 0);
        }
    }

#pragma unroll
    for (int nt = 0; nt < 12; nt++) {
        float bias = gate_b[nt * 16 + lane16];
#pragma unroll
        for (int r = 0; r < 4; r++) {
            int rowloc = quad * 4 + r;
            size_t idx = (size_t)(row0 + rowloc) * FEATD + nt * 16 + lane16;
            float z = acc[nt][r] + bias;
            float g = 1.f / (1.f + __expf(-z));
            float pf = bf2f(L[rowloc * LSTR + nt * 16 + lane16]);
            dout[idx] = pf + g * (oreg[nt][r] - pf);
        }
    }
}

extern "C" void kernel_launch(void* const* d_in, const int* in_sizes, int n_in,
                              void* d_out, int out_size, void* d_ws, size_t ws_size,
                              hipStream_t stream) {
    (void)in_sizes; (void)n_in; (void)out_size; (void)ws_size;
    const float* features = (const float*)d_in[0];
    const float* rel_emb  = (const float*)d_in[1];
    const float* proxy    = (const float*)d_in[2];
    const float* gate_w   = (const float*)d_in[3];
    const float* gate_b   = (const float*)d_in[4];
    const float* attn_k   = (const float*)d_in[5];
    const int*   adj      = (const int*)d_in[6];
    const int*   r_index  = (const int*)d_in[7];
    // d_in[8] (r_val) unused: positive scale cancels under l2norm; r_index[0]==arange(E).

    unsigned short* fin0 = (unsigned short*)d_ws;           // N*64 bf16
    unsigned short* fin1 = fin0 + (size_t)N_NODES * 64;     // N*64 bf16
    unsigned short* fin2 = fin1 + (size_t)N_NODES * 64;     // N*64 bf16
    float* reln    = (float*)(fin2 + (size_t)N_NODES * 64); // 500*64 fp32 (19.2MB off, 16B-aligned)
    float* expdot  = reln + RSZ * 64;                       // 2*500
    float* pninv   = expdot + 2 * RSZ;                      // 64
    unsigned short* B1 = (unsigned short*)(pninv + 64);     // 12288
    unsigned short* B2 = B1 + 12288;                        // 12288
    unsigned short* B3 = B2 + 12288;                        // 36864
    unsigned int* pedge = (unsigned int*)(B3 + 36864);      // NEDGE u32

    const int* src = adj + NEDGE;       // adj[1]
    const int* rel = r_index + NEDGE;   // r_index[1]

    k_prep  <<<dim3(4678), dim3(256), 0, stream>>>(features, rel_emb, attn_k, proxy, gate_w,
                                                   src, rel, fin0, reln, expdot,
                                                   pninv, B1, B2, B3, pedge);
    k_layer <<<dim3(LGRID), dim3(256), 0, stream>>>(pedge, reln, expdot,       fin0, fin1);
    k_layer <<<dim3(LGRID), dim3(256), 0, stream>>>(pedge, reln, expdot + RSZ, fin1, fin2);
    k_gate  <<<dim3(782),  dim3(256), 0, stream>>>(fin0, fin1, fin2, B1, B2, B3, pninv,
                                                   gate_b, (float*)d_out);
}